// Round 7
// baseline (263.178 us; speedup 1.0000x reference)
//
#include <hip/hip_runtime.h>
#include <math.h>

#define Bn 16
#define Hh 512
#define Ww 512
#define HW_ (Hh * Ww)

// ---------------- kernel 2 geometry (tile 32) ----------------
#define TILE 32
#define NTHREADS 1024
#define HALO 34               // conv2 input halo (TILE+2)
#define NPOS (HALO * HALO)    // 1156

typedef __bf16 bfrag  __attribute__((ext_vector_type(8)));
typedef float  ffrag  __attribute__((ext_vector_type(16)));

__device__ __forceinline__ short f2bf(float f) {           // RNE fp32 -> bf16 bits
    unsigned u = __float_as_uint(f);
    unsigned r = u + 0x7FFFu + ((u >> 16) & 1u);
    return (short)(r >> 16);
}

// gelu(x) ~= x * sigmoid(2*0.7978845608*(x + 0.044715 x^3)), ~8 VALU inst
__device__ __forceinline__ float gelu_fast(float x) {
    float z = x * x;
    float a = fmaf(z, 0.044715f, 1.0f);
    float m = x * 2.302208199f;            // x * 2*0.7978845608*log2(e)
    float u = m * a;
    float e = __builtin_amdgcn_exp2f(u);
    float r = __builtin_amdgcn_rcpf(e + 1.0f);
    return x - x * r;                      // x * e/(e+1)
}

// ---- pre-pass: pack w2 B-fragments + transpose w1 into d_ws ----
// ws ints  [0, 2304)    : B2 frags [tap][lane] 16B. B2[k=ci][n=co], lane n=l31, k=lh*8+j
// ws floats[2304, 2736) : w1t[j][co] = w1[co*27+j]  (432 floats)
__global__ void pack_w(const float* __restrict__ w2, const float* __restrict__ w1,
                       int* __restrict__ ws) {
    const int lane = threadIdx.x;            // 64 threads
    const int l31  = lane & 31;
    const int lh   = lane >> 5;
    for (int tap = 0; tap < 9; ++tap) {
        int pk[4];
        #pragma unroll
        for (int jj = 0; jj < 4; ++jj) {
            float v0 = (l31 < 18) ? w2[(l31 * 16 + lh * 8 + 2 * jj    ) * 9 + tap] : 0.0f;
            float v1 = (l31 < 18) ? w2[(l31 * 16 + lh * 8 + 2 * jj + 1) * 9 + tap] : 0.0f;
            pk[jj] = ((int)(unsigned short)f2bf(v0)) | ((int)f2bf(v1) << 16);
        }
        ((int4*)ws)[tap * 64 + lane] = make_int4(pk[0], pk[1], pk[2], pk[3]);
    }
    float* w1t = (float*)(ws + 2304);
    for (int idx = lane; idx < 432; idx += 64) {
        int co = idx & 15;
        int j  = idx >> 4;
        w1t[idx] = w1[co * 27 + j];
    }
}

// ================= split path: kernel 1 — conv1 + GELU -> bf16 feat =================
// feat layout: int4[(b*2 + half)*HW_ + y*Ww + x], half = ci-group (0: ci 0-7, 1: ci 8-15)
__global__ __launch_bounds__(256, 4) void conv1_feat(
    const float* __restrict__ wind,   // (16,2,512,512)
    const float* __restrict__ topo,   // (16,1,512,512)
    const float* __restrict__ b1,     // (16)
    const int*   __restrict__ wsB,    // w1t at +2304
    int4* __restrict__ feat)          // 134 MB bf16 feat
{
    __shared__ float s_in[3][18][18];          // 3.9 KB

    const int tid = threadIdx.x;
    const int bb  = blockIdx.z;
    const int ty0 = blockIdx.y * 16;
    const int tx0 = blockIdx.x * 16;

    const float* w1t = (const float*)(wsB + 2304);

    // stage 18x18x3 input halo (zero outside image = conv1 zero padding)
    for (int idx = tid; idx < 3 * 18 * 18; idx += 256) {
        int c   = idx / 324;
        int rem = idx - c * 324;
        int ly  = rem / 18;
        int lx  = rem - ly * 18;
        int gy  = ty0 - 1 + ly;
        int gx  = tx0 - 1 + lx;
        float v = 0.0f;
        if (gy >= 0 && gy < Hh && gx >= 0 && gx < Ww) {
            if (c < 2) v = wind[(bb * 2 + c) * HW_ + gy * Ww + gx];
            else       v = topo[bb * HW_ + gy * Ww + gx];
        }
        s_in[c][ly][lx] = v;
    }
    __syncthreads();

    // exactly 1 output position per thread — perfect balance
    const int ly = tid >> 4;
    const int lx = tid & 15;
    const int y  = ty0 + ly;
    const int x  = tx0 + lx;

    float gv[16];
    #pragma unroll
    for (int co = 0; co < 16; ++co) gv[co] = b1[co];
    #pragma unroll
    for (int c = 0; c < 3; ++c)
        #pragma unroll
        for (int ky = 0; ky < 3; ++ky)
            #pragma unroll
            for (int kx = 0; kx < 3; ++kx) {
                float f = s_in[c][ly + ky][lx + kx];   // 1 ds_read, imm offset
                const float* wj = w1t + (c * 9 + ky * 3 + kx) * 16;
                #pragma unroll
                for (int co = 0; co < 16; ++co)
                    gv[co] = fmaf(f, wj[co], gv[co]);  // v_fmac with SGPR weight
            }
    #pragma unroll
    for (int co = 0; co < 16; ++co) gv[co] = gelu_fast(gv[co]);

    #pragma unroll
    for (int half = 0; half < 2; ++half) {
        int pk[4];
        #pragma unroll
        for (int jj = 0; jj < 4; ++jj) {
            pk[jj] = ((int)(unsigned short)f2bf(gv[half * 8 + 2 * jj]))
                   | ((int)f2bf(gv[half * 8 + 2 * jj + 1]) << 16);
        }
        feat[(size_t)(bb * 2 + half) * HW_ + y * Ww + x] = make_int4(pk[0], pk[1], pk[2], pk[3]);
    }
}

// ================= split path: kernel 2 — conv2 MFMA + deform sampling =================
// LDS: s_feat bf16[2][1156][8] = 36992 B @ 0 (live until post-MFMA barrier)
//      s_off  float[1024][19]  = 77824 B @ 0 (aliases; written after barrier)
#define SMEM2 77824

__global__ __launch_bounds__(NTHREADS, 8) void conv2_sample(
    const float* __restrict__ pm25,   // (16,1,512,512)
    const float* __restrict__ b2,     // (18)
    const float* __restrict__ wt,     // (9)
    const int*   __restrict__ wsB,    // packed w2 B-fragments
    const int4*  __restrict__ feat,   // bf16 feat from kernel1
    float* __restrict__ out)          // (16,1,512,512)
{
    __shared__ __align__(16) char smem[SMEM2];
    __bf16* s_feat = (__bf16*)smem;             // [2][1156][8]
    float*  s_off  = (float*)smem;              // [1024][19]

    const int tid = threadIdx.x;
    const int bb  = blockIdx.z;
    const int ty0 = blockIdx.y * TILE;
    const int tx0 = blockIdx.x * TILE;

    const int lane = tid & 63;
    const int wv   = tid >> 6;       // 0..15
    const int l31  = lane & 31;
    const int lh   = lane >> 5;

    // ---- stage feat halo 34x34 x 2 halves (16B chunks, zero-pad OOB) ----
    for (int u = tid; u < 2 * NPOS; u += NTHREADS) {
        int half = (u >= NPOS) ? 1 : 0;
        int pos  = u - half * NPOS;
        int ly   = pos / HALO;
        int lx   = pos - ly * HALO;
        int gy   = ty0 - 1 + ly;
        int gx   = tx0 - 1 + lx;
        int4 v   = make_int4(0, 0, 0, 0);
        if (gy >= 0 && gy < Hh && gx >= 0 && gx < Ww)
            v = feat[(size_t)(bb * 2 + half) * HW_ + gy * Ww + gx];
        *(int4*)&s_feat[(size_t)u * 8] = v;
    }
    __syncthreads();

    // ---- conv2 via MFMA 32x32x16 bf16 (16 waves; M=1024 px, N=18, K=16x9) ----
    ffrag acc0, acc1;
    #pragma unroll
    for (int r = 0; r < 16; ++r) { acc0[r] = 0.0f; acc1[r] = 0.0f; }
    {
        const int m0   = wv * 64 + l31;
        const int m1   = m0 + 32;
        const int tyA0 = m0 >> 5, txA0 = m0 & 31;
        const int tyA1 = m1 >> 5, txA1 = m1 & 31;
        const bfrag* Bf = (const bfrag*)wsB;

        #pragma unroll
        for (int tap = 0; tap < 9; ++tap) {
            const int ky = tap / 3;
            const int kx = tap - ky * 3;
            bfrag b = Bf[tap * 64 + lane];
            const int p0 = (tyA0 + ky) * HALO + (txA0 + kx);
            const int p1 = (tyA1 + ky) * HALO + (txA1 + kx);
            bfrag a0 = *(const bfrag*)&s_feat[(lh * NPOS + p0) * 8];
            bfrag a1 = *(const bfrag*)&s_feat[(lh * NPOS + p1) * 8];
            acc0 = __builtin_amdgcn_mfma_f32_32x32x16_bf16(a0, b, acc0, 0, 0, 0);
            acc1 = __builtin_amdgcn_mfma_f32_32x32x16_bf16(a1, b, acc1, 0, 0, 0);
        }
    }
    __syncthreads();   // all feat reads done before s_off overwrites

    // ---- write D (+bias) to s_off[m][co] (stride 19) ----
    // C/D layout: col(co)=lane&31, row=(reg&3)+8*(reg>>2)+4*(lane>>5)
    if (l31 < 18) {
        float bias = b2[l31];
        #pragma unroll
        for (int reg = 0; reg < 16; ++reg) {
            int row = (reg & 3) + 8 * (reg >> 2) + 4 * lh;
            s_off[(wv * 64 + row) * 19 + l31]      = acc0[reg] + bias;
            s_off[(wv * 64 + 32 + row) * 19 + l31] = acc1[reg] + bias;
        }
    }
    __syncthreads();

    // ---- deformable 3x3 bilinear sampling of pm25, weighted by wt ----
    {
        const int ty = tid >> 5;
        const int tx = tid & 31;
        const int y  = ty0 + ty;
        const int x  = tx0 + tx;
        const float* img  = pm25 + bb * HW_;
        const float* offp = s_off + tid * 19;

        float o = 0.0f;
        #pragma unroll
        for (int k = 0; k < 9; ++k) {
            float wk = wt[k];               // wave-uniform
            if (wk != 0.0f) {               // uniform branch: skips zero taps
                float dy = offp[2 * k];
                float dx = offp[2 * k + 1];
                float py = (float)y + (float)(k / 3 - 1) + dy;
                float px = (float)x + (float)(k % 3 - 1) + dx;
                float y0f = floorf(py), x0f = floorf(px);
                float wy = py - y0f, wx = px - x0f;
                int y0 = (int)y0f, x0 = (int)x0f;

                auto corner = [&](int yi, int xi) -> float {
                    bool valid = (yi >= 0) && (yi < Hh) && (xi >= 0) && (xi < Ww);
                    int yc = min(max(yi, 0), Hh - 1);
                    int xc = min(max(xi, 0), Ww - 1);
                    float v = img[yc * Ww + xc];
                    return valid ? v : 0.0f;
                };

                float v00 = corner(y0,     x0);
                float v01 = corner(y0,     x0 + 1);
                float v10 = corner(y0 + 1, x0);
                float v11 = corner(y0 + 1, x0 + 1);

                o += wk * ((1.0f - wy) * ((1.0f - wx) * v00 + wx * v01) +
                           wy          * ((1.0f - wx) * v10 + wx * v11));
            }
        }
        out[bb * HW_ + y * Ww + x] = o;
    }
}

// ================= fallback: R6 fused kernel (used if ws too small for feat) =================
#define INH 36
#define SMEM_BYTES 77824

__global__ __launch_bounds__(NTHREADS, 8) void residual_advection_fused(
    const float* __restrict__ pm25,
    const float* __restrict__ wind,
    const float* __restrict__ topo,
    const float* __restrict__ b1,
    const float* __restrict__ b2,
    const float* __restrict__ wt,
    const int*   __restrict__ wsB,
    float* __restrict__ out)
{
    __shared__ __align__(16) char smem[SMEM_BYTES];
    float (*s_in)[INH][INH] = (float (*)[INH][INH])smem;
    __bf16* s_feat = (__bf16*)(smem + 15552);
    float*  s_off  = (float*)smem;

    const int tid = threadIdx.x;
    const int bb  = blockIdx.z;
    const int ty0 = blockIdx.y * TILE;
    const int tx0 = blockIdx.x * TILE;

    const int lane = tid & 63;
    const int wv   = tid >> 6;
    const int l31  = lane & 31;
    const int lh   = lane >> 5;

    const float* w1t = (const float*)(wsB + 2304);

    for (int idx = tid; idx < 3 * INH * INH; idx += NTHREADS) {
        int c   = idx / (INH * INH);
        int rem = idx - c * (INH * INH);
        int ly  = rem / INH;
        int lx  = rem - ly * INH;
        int gy  = ty0 - 2 + ly;
        int gx  = tx0 - 2 + lx;
        float v = 0.0f;
        if (gy >= 0 && gy < Hh && gx >= 0 && gx < Ww) {
            if (c < 2) v = wind[(bb * 2 + c) * HW_ + gy * Ww + gx];
            else       v = topo[bb * HW_ + gy * Ww + gx];
        }
        s_in[c][ly][lx] = v;
    }
    __syncthreads();

    for (int pos = tid; pos < NPOS; pos += NTHREADS) {
        int ly = pos / HALO;
        int lx = pos - ly * HALO;
        int gy = ty0 - 1 + ly;
        int gx = tx0 - 1 + lx;
        float gv[16];
        if (gy >= 0 && gy < Hh && gx >= 0 && gx < Ww) {
            #pragma unroll
            for (int co = 0; co < 16; ++co) gv[co] = b1[co];
            #pragma unroll
            for (int c = 0; c < 3; ++c)
                #pragma unroll
                for (int ky = 0; ky < 3; ++ky)
                    #pragma unroll
                    for (int kx = 0; kx < 3; ++kx) {
                        float f = s_in[c][ly + ky][lx + kx];
                        const float* wj = w1t + (c * 9 + ky * 3 + kx) * 16;
                        #pragma unroll
                        for (int co = 0; co < 16; ++co)
                            gv[co] = fmaf(f, wj[co], gv[co]);
                    }
            #pragma unroll
            for (int co = 0; co < 16; ++co) gv[co] = gelu_fast(gv[co]);
        } else {
            #pragma unroll
            for (int co = 0; co < 16; ++co) gv[co] = 0.0f;
        }
        #pragma unroll
        for (int half = 0; half < 2; ++half) {
            int pk[4];
            #pragma unroll
            for (int jj = 0; jj < 4; ++jj) {
                pk[jj] = ((int)(unsigned short)f2bf(gv[half * 8 + 2 * jj]))
                       | ((int)f2bf(gv[half * 8 + 2 * jj + 1]) << 16);
            }
            *(int4*)&s_feat[(half * NPOS + pos) * 8] = make_int4(pk[0], pk[1], pk[2], pk[3]);
        }
    }
    __syncthreads();

    ffrag acc0, acc1;
    #pragma unroll
    for (int r = 0; r < 16; ++r) { acc0[r] = 0.0f; acc1[r] = 0.0f; }
    {
        const int m0   = wv * 64 + l31;
        const int m1   = m0 + 32;
        const int tyA0 = m0 >> 5, txA0 = m0 & 31;
        const int tyA1 = m1 >> 5, txA1 = m1 & 31;
        const bfrag* Bf = (const bfrag*)wsB;

        #pragma unroll
        for (int tap = 0; tap < 9; ++tap) {
            const int ky = tap / 3;
            const int kx = tap - ky * 3;
            bfrag b = Bf[tap * 64 + lane];
            const int p0 = (tyA0 + ky) * HALO + (txA0 + kx);
            const int p1 = (tyA1 + ky) * HALO + (txA1 + kx);
            bfrag a0 = *(const bfrag*)&s_feat[(lh * NPOS + p0) * 8];
            bfrag a1 = *(const bfrag*)&s_feat[(lh * NPOS + p1) * 8];
            acc0 = __builtin_amdgcn_mfma_f32_32x32x16_bf16(a0, b, acc0, 0, 0, 0);
            acc1 = __builtin_amdgcn_mfma_f32_32x32x16_bf16(a1, b, acc1, 0, 0, 0);
        }
    }
    __syncthreads();

    if (l31 < 18) {
        float bias = b2[l31];
        #pragma unroll
        for (int reg = 0; reg < 16; ++reg) {
            int row = (reg & 3) + 8 * (reg >> 2) + 4 * lh;
            s_off[(wv * 64 + row) * 19 + l31]      = acc0[reg] + bias;
            s_off[(wv * 64 + 32 + row) * 19 + l31] = acc1[reg] + bias;
        }
    }
    __syncthreads();

    {
        const int ty = tid >> 5;
        const int tx = tid & 31;
        const int y  = ty0 + ty;
        const int x  = tx0 + tx;
        const float* img  = pm25 + bb * HW_;
        const float* offp = s_off + tid * 19;

        float o = 0.0f;
        #pragma unroll
        for (int k = 0; k < 9; ++k) {
            float wk = wt[k];
            if (wk != 0.0f) {
                float dy = offp[2 * k];
                float dx = offp[2 * k + 1];
                float py = (float)y + (float)(k / 3 - 1) + dy;
                float px = (float)x + (float)(k % 3 - 1) + dx;
                float y0f = floorf(py), x0f = floorf(px);
                float wy = py - y0f, wx = px - x0f;
                int y0 = (int)y0f, x0 = (int)x0f;

                auto corner = [&](int yi, int xi) -> float {
                    bool valid = (yi >= 0) && (yi < Hh) && (xi >= 0) && (xi < Ww);
                    int yc = min(max(yi, 0), Hh - 1);
                    int xc = min(max(xi, 0), Ww - 1);
                    float v = img[yc * Ww + xc];
                    return valid ? v : 0.0f;
                };

                float v00 = corner(y0,     x0);
                float v01 = corner(y0,     x0 + 1);
                float v10 = corner(y0 + 1, x0);
                float v11 = corner(y0 + 1, x0 + 1);

                o += wk * ((1.0f - wy) * ((1.0f - wx) * v00 + wx * v01) +
                           wy          * ((1.0f - wx) * v10 + wx * v11));
            }
        }
        out[bb * HW_ + y * Ww + x] = o;
    }
}

extern "C" void kernel_launch(void* const* d_in, const int* in_sizes, int n_in,
                              void* d_out, int out_size, void* d_ws, size_t ws_size,
                              hipStream_t stream) {
    const float* pm25 = (const float*)d_in[0];
    const float* wind = (const float*)d_in[1];
    const float* topo = (const float*)d_in[2];
    const float* w1   = (const float*)d_in[3];
    const float* b1   = (const float*)d_in[4];
    const float* w2   = (const float*)d_in[5];
    const float* b2   = (const float*)d_in[6];
    const float* wt   = (const float*)d_in[7];
    float* o          = (float*)d_out;
    int*   wsB        = (int*)d_ws;   // packs: 9216 + 1728 bytes at base

    pack_w<<<dim3(1), dim3(64), 0, stream>>>(w2, w1, wsB);

    const size_t feat_bytes = (size_t)Bn * 2 * HW_ * 16;      // 134 MB
    const size_t need       = 16384 + feat_bytes;

    if (ws_size >= need) {
        int4* feat = (int4*)((char*)d_ws + 16384);
        conv1_feat<<<dim3(Ww / 16, Hh / 16, Bn), dim3(256), 0, stream>>>(
            wind, topo, b1, wsB, feat);
        conv2_sample<<<dim3(Ww / TILE, Hh / TILE, Bn), dim3(NTHREADS), 0, stream>>>(
            pm25, b2, wt, wsB, feat, o);
    } else {
        residual_advection_fused<<<dim3(Ww / TILE, Hh / TILE, Bn), dim3(NTHREADS), 0, stream>>>(
            pm25, wind, topo, b1, b2, wt, wsB, o);
    }
}

// Round 8
// 221.372 us; speedup vs baseline: 1.1888x; 1.1888x over previous
//
#include <hip/hip_runtime.h>
#include <math.h>

#define Bn 16
#define Hh 512
#define Ww 512
#define HW_ (Hh * Ww)
#define TILE 32
#define NTHREADS 1024
#define HALO 34               // conv2 input halo (TILE+2)
#define INH 36                // conv1 input halo (TILE+4)
#define NPOS (HALO * HALO)    // 1156

typedef __bf16 bfrag  __attribute__((ext_vector_type(8)));
typedef float  ffrag  __attribute__((ext_vector_type(16)));
typedef float  f32x2  __attribute__((ext_vector_type(2)));

__device__ __forceinline__ short f2bf(float f) {           // RNE fp32 -> bf16 bits
    unsigned u = __float_as_uint(f);
    unsigned r = u + 0x7FFFu + ((u >> 16) & 1u);
    return (short)(r >> 16);
}

// gelu(x) ~= x*sigmoid(2*0.7978845608*(x+0.044715x^3)), vectorized over 2 lanes
__device__ __forceinline__ f32x2 gelu_fast2(f32x2 x) {
    f32x2 z = x * x;
    f32x2 a = z * 0.044715f + 1.0f;
    f32x2 u = (x * 2.302208199f) * a;      // includes log2(e) factor
    f32x2 e;
    e.x = __builtin_amdgcn_exp2f(u.x);
    e.y = __builtin_amdgcn_exp2f(u.y);
    f32x2 r;
    r.x = __builtin_amdgcn_rcpf(e.x + 1.0f);
    r.y = __builtin_amdgcn_rcpf(e.y + 1.0f);
    return x - x * r;                      // x * e/(e+1)
}

// ---- pre-pass: pack w2 B-fragments + transpose w1 into d_ws ----
// ws ints  [0, 2304)    : B2 frags [tap][lane] 16B. B2[k=ci][n=co], lane n=l31, k=lh*8+j
// ws floats[2304, 2736) : w1t[j][co] = w1[co*27+j]  (432 floats)
__global__ void pack_w(const float* __restrict__ w2, const float* __restrict__ w1,
                       int* __restrict__ ws) {
    const int lane = threadIdx.x;            // 64 threads
    const int l31  = lane & 31;
    const int lh   = lane >> 5;
    for (int tap = 0; tap < 9; ++tap) {
        int pk[4];
        #pragma unroll
        for (int jj = 0; jj < 4; ++jj) {
            float v0 = (l31 < 18) ? w2[(l31 * 16 + lh * 8 + 2 * jj    ) * 9 + tap] : 0.0f;
            float v1 = (l31 < 18) ? w2[(l31 * 16 + lh * 8 + 2 * jj + 1) * 9 + tap] : 0.0f;
            pk[jj] = ((int)(unsigned short)f2bf(v0)) | ((int)f2bf(v1) << 16);
        }
        ((int4*)ws)[tap * 64 + lane] = make_int4(pk[0], pk[1], pk[2], pk[3]);
    }
    float* w1t = (float*)(ws + 2304);
    for (int idx = lane; idx < 432; idx += 64) {
        int co = idx & 15;
        int j  = idx >> 4;
        w1t[idx] = w1[co * 27 + j];
    }
}

// LDS layout (bytes), regions alias across barriers:
//   s_in   float [3][36][36]  @ 0      (15552)  live P1-P2
//   s_feat bf16  [2][1156][8] @ 15552  (36992)  live P2-P3 (conv2 A-matrix)
//   s_off  float [1024][19]   @ 0      (77824)  live P4-P5 (aliases s_in+s_feat,
//                                               written only after all feat reads)
#define SMEM_BYTES 77824

__global__ __launch_bounds__(NTHREADS, 8) void residual_advection_fused(
    const float* __restrict__ pm25,   // (16,1,512,512)
    const float* __restrict__ wind,   // (16,2,512,512)
    const float* __restrict__ topo,   // (16,1,512,512)
    const float* __restrict__ b1,     // (16)
    const float* __restrict__ b2,     // (18)
    const float* __restrict__ wt,     // (9)
    const int*   __restrict__ wsB,    // packed w2 B-fragments + w1t
    float* __restrict__ out)          // (16,1,512,512)
{
    __shared__ __align__(16) char smem[SMEM_BYTES];
    float (*s_in)[INH][INH] = (float (*)[INH][INH])smem;
    __bf16* s_feat = (__bf16*)(smem + 15552);   // [2][1156][8]
    float*  s_off  = (float*)smem;              // [1024][19]

    const int tid = threadIdx.x;
    const int bb  = blockIdx.z;
    const int ty0 = blockIdx.y * TILE;
    const int tx0 = blockIdx.x * TILE;

    const int lane = tid & 63;
    const int wv   = tid >> 6;       // 0..15
    const int l31  = lane & 31;
    const int lh   = lane >> 5;

    const float* w1t = (const float*)(wsB + 2304);

    // ---- P1: stage input halo (zero outside image = conv1 zero padding) ----
    for (int idx = tid; idx < 3 * INH * INH; idx += NTHREADS) {
        int c   = idx / (INH * INH);
        int rem = idx - c * (INH * INH);
        int ly  = rem / INH;
        int lx  = rem - ly * INH;
        int gy  = ty0 - 2 + ly;
        int gx  = tx0 - 2 + lx;
        float v = 0.0f;
        if (gy >= 0 && gy < Hh && gx >= 0 && gx < Ww) {
            if (c < 2) v = wind[(bb * 2 + c) * HW_ + gy * Ww + gx];
            else       v = topo[bb * HW_ + gy * Ww + gx];
        }
        s_in[c][ly][lx] = v;
    }
    __syncthreads();

    // ---- P2a: conv1 positions 0..1023, one per thread, 16 ch (pk-fma) ----
    {
        const int pos = tid;
        const int ly = pos / HALO;
        const int lx = pos - ly * HALO;
        const int gy = ty0 - 1 + ly;
        const int gx = tx0 - 1 + lx;
        f32x2 gv[8];
        if (gy >= 0 && gy < Hh && gx >= 0 && gx < Ww) {
            #pragma unroll
            for (int p = 0; p < 8; ++p) gv[p] = *(const f32x2*)&b1[2 * p];
            #pragma unroll
            for (int c = 0; c < 3; ++c)
                #pragma unroll
                for (int ky = 0; ky < 3; ++ky)
                    #pragma unroll
                    for (int kx = 0; kx < 3; ++kx) {
                        float f = s_in[c][ly + ky][lx + kx];   // 1 ds_read
                        f32x2 f2; f2.x = f; f2.y = f;
                        const f32x2* wj = (const f32x2*)(w1t + (c * 9 + ky * 3 + kx) * 16);
                        #pragma unroll
                        for (int p = 0; p < 8; ++p)
                            gv[p] += f2 * wj[p];               // v_pk_fma_f32, SGPR weight
                    }
            #pragma unroll
            for (int p = 0; p < 8; ++p) gv[p] = gelu_fast2(gv[p]);
        } else {
            #pragma unroll
            for (int p = 0; p < 8; ++p) gv[p] = 0.0f;          // conv2 zero-padding
        }
        #pragma unroll
        for (int half = 0; half < 2; ++half) {
            int pk[4];
            #pragma unroll
            for (int jj = 0; jj < 4; ++jj) {
                f32x2 v = gv[half * 4 + jj];
                pk[jj] = ((int)(unsigned short)f2bf(v.x)) | ((int)f2bf(v.y) << 16);
            }
            *(int4*)&s_feat[(half * NPOS + pos) * 8] = make_int4(pk[0], pk[1], pk[2], pk[3]);
        }
    }

    // ---- P2b: conv1 positions 1024..1155 as 528 channel-quad items ----
    if (tid < 528) {
        const int quad = tid & 3;             // 4 channels each
        const int pos  = 1024 + (tid >> 2);
        const int ly = pos / HALO;
        const int lx = pos - ly * HALO;
        const int gy = ty0 - 1 + ly;
        const int gx = tx0 - 1 + lx;
        const int cb = quad * 4;
        f32x2 gv0, gv1;
        if (gy >= 0 && gy < Hh && gx >= 0 && gx < Ww) {
            gv0 = *(const f32x2*)&b1[cb];
            gv1 = *(const f32x2*)&b1[cb + 2];
            #pragma unroll
            for (int c = 0; c < 3; ++c)
                #pragma unroll
                for (int ky = 0; ky < 3; ++ky)
                    #pragma unroll
                    for (int kx = 0; kx < 3; ++kx) {
                        float f = s_in[c][ly + ky][lx + kx];
                        f32x2 f2; f2.x = f; f2.y = f;
                        const float* wj = w1t + (c * 9 + ky * 3 + kx) * 16 + cb;
                        gv0 += f2 * *(const f32x2*)wj;
                        gv1 += f2 * *(const f32x2*)(wj + 2);
                    }
            gv0 = gelu_fast2(gv0);
            gv1 = gelu_fast2(gv1);
        } else {
            gv0 = 0.0f; gv1 = 0.0f;
        }
        int2 pk;
        pk.x = ((int)(unsigned short)f2bf(gv0.x)) | ((int)f2bf(gv0.y) << 16);
        pk.y = ((int)(unsigned short)f2bf(gv1.x)) | ((int)f2bf(gv1.y) << 16);
        *(int2*)&s_feat[((quad >> 1) * NPOS + pos) * 8 + (quad & 1) * 4] = pk;
    }
    __syncthreads();

    // ---- P3: conv2 via MFMA 32x32x16 bf16 (16 waves; M=1024 px, N=18, K=16x9) ----
    ffrag acc0, acc1;
    #pragma unroll
    for (int r = 0; r < 16; ++r) { acc0[r] = 0.0f; acc1[r] = 0.0f; }
    {
        const int m0   = wv * 64 + l31;
        const int m1   = m0 + 32;
        const int tyA0 = m0 >> 5, txA0 = m0 & 31;
        const int tyA1 = m1 >> 5, txA1 = m1 & 31;
        const bfrag* Bf = (const bfrag*)wsB;

        #pragma unroll
        for (int tap = 0; tap < 9; ++tap) {
            const int ky = tap / 3;
            const int kx = tap - ky * 3;
            bfrag b = Bf[tap * 64 + lane];
            const int p0 = (tyA0 + ky) * HALO + (txA0 + kx);
            const int p1 = (tyA1 + ky) * HALO + (txA1 + kx);
            bfrag a0 = *(const bfrag*)&s_feat[(lh * NPOS + p0) * 8];
            bfrag a1 = *(const bfrag*)&s_feat[(lh * NPOS + p1) * 8];
            acc0 = __builtin_amdgcn_mfma_f32_32x32x16_bf16(a0, b, acc0, 0, 0, 0);
            acc1 = __builtin_amdgcn_mfma_f32_32x32x16_bf16(a1, b, acc1, 0, 0, 0);
        }
    }
    __syncthreads();   // all feat reads done before s_off overwrites

    // ---- P4: write D (+bias) to s_off[m][co] (stride 19) ----
    // C/D layout: col(co)=lane&31, row=(reg&3)+8*(reg>>2)+4*(lane>>5)
    if (l31 < 18) {
        float bias = b2[l31];
        #pragma unroll
        for (int reg = 0; reg < 16; ++reg) {
            int row = (reg & 3) + 8 * (reg >> 2) + 4 * lh;
            s_off[(wv * 64 + row) * 19 + l31]      = acc0[reg] + bias;
            s_off[(wv * 64 + 32 + row) * 19 + l31] = acc1[reg] + bias;
        }
    }
    __syncthreads();

    // ---- P5: deformable 3x3 bilinear sampling of pm25, weighted by wt ----
    {
        const int ty = tid >> 5;
        const int tx = tid & 31;
        const int y  = ty0 + ty;
        const int x  = tx0 + tx;
        const float* img  = pm25 + bb * HW_;
        const float* offp = s_off + tid * 19;

        float o = 0.0f;
        #pragma unroll
        for (int k = 0; k < 9; ++k) {
            float wk = wt[k];               // wave-uniform
            if (wk != 0.0f) {               // uniform branch: skips zero taps
                float dy = offp[2 * k];
                float dx = offp[2 * k + 1];
                float py = (float)y + (float)(k / 3 - 1) + dy;
                float px = (float)x + (float)(k % 3 - 1) + dx;
                float y0f = floorf(py), x0f = floorf(px);
                float wy = py - y0f, wx = px - x0f;
                int y0 = (int)y0f, x0 = (int)x0f;

                auto corner = [&](int yi, int xi) -> float {
                    bool valid = (yi >= 0) && (yi < Hh) && (xi >= 0) && (xi < Ww);
                    int yc = min(max(yi, 0), Hh - 1);
                    int xc = min(max(xi, 0), Ww - 1);
                    float v = img[yc * Ww + xc];
                    return valid ? v : 0.0f;
                };

                float v00 = corner(y0,     x0);
                float v01 = corner(y0,     x0 + 1);
                float v10 = corner(y0 + 1, x0);
                float v11 = corner(y0 + 1, x0 + 1);

                o += wk * ((1.0f - wy) * ((1.0f - wx) * v00 + wx * v01) +
                           wy          * ((1.0f - wx) * v10 + wx * v11));
            }
        }
        out[bb * HW_ + y * Ww + x] = o;
    }
}

extern "C" void kernel_launch(void* const* d_in, const int* in_sizes, int n_in,
                              void* d_out, int out_size, void* d_ws, size_t ws_size,
                              hipStream_t stream) {
    const float* pm25 = (const float*)d_in[0];
    const float* wind = (const float*)d_in[1];
    const float* topo = (const float*)d_in[2];
    const float* w1   = (const float*)d_in[3];
    const float* b1   = (const float*)d_in[4];
    const float* w2   = (const float*)d_in[5];
    const float* b2   = (const float*)d_in[6];
    const float* wt   = (const float*)d_in[7];
    float* o          = (float*)d_out;
    int*   wsB        = (int*)d_ws;   // 9216 B frags + 1728 B w1t = 10944 B

    pack_w<<<dim3(1), dim3(64), 0, stream>>>(w2, w1, wsB);

    dim3 grid(Ww / TILE, Hh / TILE, Bn);
    residual_advection_fused<<<grid, dim3(NTHREADS), 0, stream>>>(
        pm25, wind, topo, b1, b2, wt, wsB, o);
}